// Round 7
// baseline (400.637 us; speedup 1.0000x reference)
//
#include <hip/hip_runtime.h>
#include <math.h>

#define NB 2
#define NS 8192
#define NE 128
#define NROWS (NB * NS)
#define RS 132          // qkv fp32 LDS row stride
#define PART_STRIDE 8448

typedef __attribute__((ext_vector_type(8))) short s8v;    // 8 bf16 MFMA frag
typedef __attribute__((ext_vector_type(16))) float fx16;  // 32x32 accumulator

static __device__ __forceinline__ unsigned short f2bf(float x) {
    unsigned int u = __float_as_uint(x);
    u += 0x7FFFu + ((u >> 16) & 1u);
    return (unsigned short)(u >> 16);
}
static __device__ __forceinline__ unsigned int pkbf(float a, float b) {
    unsigned int ua = __float_as_uint(a), ub = __float_as_uint(b);
    ua += 0x7FFFu + ((ua >> 16) & 1u);
    ub += 0x7FFFu + ((ub >> 16) & 1u);
    return (ua >> 16) | (ub & 0xFFFF0000u);
}

// ---------------------------------------------------------------------------
// QKV projection fp32->bf16. Q pre-scaled by log2(e)/sqrt(E). V written
// transposed Vt[b][d][key] via LDS transpose -> full-line 64B stores.
// grid (NROWS/32, 3, 2), block 256.
// ---------------------------------------------------------------------------
__global__ __launch_bounds__(256, 2)
void qkv_kernel(const float* __restrict__ x,
                const float* __restrict__ Wq, const float* __restrict__ bq,
                const float* __restrict__ Wk, const float* __restrict__ bk,
                const float* __restrict__ Wv, const float* __restrict__ bv,
                unsigned short* __restrict__ qkv)
{
    __shared__ float xL[32 * RS];
    __shared__ float wL[64 * RS];

    const int t    = threadIdx.x;
    const int row0 = blockIdx.x * 32;
    const int mat  = blockIdx.y;
    const int oh   = blockIdx.z * 64;

    const float* W    = (mat == 0) ? Wq : (mat == 1) ? Wk : Wv;
    const float* bias = (mat == 0) ? bq : (mat == 1) ? bk : bv;
    unsigned short* out = qkv + (size_t)mat * NROWS * NE;
    const float osc = (mat == 0) ? 0.12751743f : 1.0f;   // log2(e)/sqrt(128)

    #pragma unroll
    for (int i = 0; i < 4; ++i) {
        int v = t + i * 256;
        int r = v >> 5, c = v & 31;
        *(float4*)&xL[r * RS + c * 4] =
            *(const float4*)&x[(size_t)(row0 + r) * NE + c * 4];
    }
    #pragma unroll
    for (int i = 0; i < 8; ++i) {
        int v = t + i * 256;
        int r = v >> 5, c = v & 31;
        *(float4*)&wL[r * RS + c * 4] =
            *(const float4*)&W[(size_t)(oh + r) * NE + c * 4];
    }
    __syncthreads();

    const int tq = t >> 4, tk = t & 15;
    const int r0 = 2 * tq;

    float acc[2][4] = {};
    #pragma unroll 4
    for (int c = 0; c < 32; ++c) {
        float4 xa = *(const float4*)&xL[r0 * RS + c * 4];
        float4 xb = *(const float4*)&xL[(r0 + 1) * RS + c * 4];
        #pragma unroll
        for (int j = 0; j < 4; ++j) {
            float4 w4 = *(const float4*)&wL[(tk + 16 * j) * RS + c * 4];
            acc[0][j] = fmaf(xa.x, w4.x, fmaf(xa.y, w4.y,
                        fmaf(xa.z, w4.z, fmaf(xa.w, w4.w, acc[0][j]))));
            acc[1][j] = fmaf(xb.x, w4.x, fmaf(xb.y, w4.y,
                        fmaf(xb.z, w4.z, fmaf(xb.w, w4.w, acc[1][j]))));
        }
    }

    if (mat != 2) {
        #pragma unroll
        for (int i = 0; i < 2; ++i)
            #pragma unroll
            for (int j = 0; j < 4; ++j) {
                int o = tk + 16 * j;
                float val = (acc[i][j] + bias[oh + o]) * osc;
                out[(size_t)(row0 + r0 + i) * NE + oh + o] = f2bf(val);
            }
    } else {
        // LDS transpose: vT[o][keyword], 20-word row stride (conflict-free)
        __syncthreads();
        unsigned int* vT = (unsigned int*)xL;   // 64 * 20 words = 5120 B
        #pragma unroll
        for (int j = 0; j < 4; ++j) {
            int o = tk + 16 * j;
            float bb2 = bias[oh + o];
            vT[o * 20 + tq] = pkbf(acc[0][j] + bb2, acc[1][j] + bb2);
        }
        __syncthreads();
        int o = t >> 2, c = t & 3;
        uint4 w4 = *(uint4*)&vT[o * 20 + c * 4];
        int bb = row0 >> 13, key0 = row0 & (NS - 1);
        *(uint4*)&out[(((size_t)(bb * NE + oh + o)) << 13) + key0 + c * 8] = w4;
    }
}

// ---------------------------------------------------------------------------
// bf16 MFMA flash attention, LDS-free main loop. grid 1024, block 256.
// Block: 32 q-rows x 4096-key half (hb); wave w owns keys [w*1024,(w+1)*1024).
// K and V fragments read DIRECTLY from global (L1/L2-resident).
// In-block 4-way merge (LDS, 3 barriers) -> fp16 partial to ws.
// LDS 33,280 B + VGPR<=128 -> 4 blocks/CU = 16 waves/CU (4/SIMD).
// ---------------------------------------------------------------------------
__global__ __launch_bounds__(256, 4)
void attn_kernel(const unsigned short* __restrict__ qkv,
                 unsigned char* __restrict__ pws)
{
    __shared__ float MB[2 * 4160];   // 2 merge regions: O 4096 + m 32 + l 32

    const int t  = threadIdx.x;
    const int id = blockIdx.x;                    // 0..1023; id&7 = XCD
    const int b  = (id >> 2) & 1;
    const int hb = (id >> 1) & 1;
    const int qt = ((id >> 3) << 1) | (id & 1);   // 0..255

    const unsigned short* Qg = qkv;
    const unsigned short* Kg = qkv + (size_t)NROWS * NE;
    const unsigned short* Vb = qkv + (size_t)2 * NROWS * NE + ((size_t)b << 20);

    const int w = t >> 6, lane = t & 63, lq = lane & 31, h = lane >> 5;
    const int qbase = b * NS + qt * 32;
    const size_t kvbatch = (size_t)b * NS * NE;

    // Q fragments (B-operand), pre-scaled by log2(e)/sqrt(E) in qkv
    s8v qf[8];
    #pragma unroll
    for (int s = 0; s < 8; ++s)
        qf[s] = *(const s8v*)(Qg + (size_t)(qbase + lq) * NE + s * 16 + h * 8);

    fx16 acc[4];
    #pragma unroll
    for (int dt = 0; dt < 4; ++dt)
        #pragma unroll
        for (int i = 0; i < 16; ++i) acc[dt][i] = 0.f;

    float m2 = -INFINITY, l = 0.f;
    const int k0w = hb * 4096 + w * 1024;

    for (int r = 0; r < 32; ++r) {
        const int key0 = k0w + r * 32;

        // ---- GEMM1: S^T[key][q] = K.Q^T, K frags direct from global ----
        fx16 st;
        #pragma unroll
        for (int i = 0; i < 16; ++i) st[i] = 0.f;
        const unsigned short* Kr = Kg + kvbatch + (size_t)(key0 + lq) * NE + h * 8;
        #pragma unroll
        for (int s = 0; s < 8; ++s) {
            s8v af = *(const s8v*)(Kr + s * 16);
            st = __builtin_amdgcn_mfma_f32_32x32x16_bf16(af, qf[s], st, 0, 0, 0);
        }

        // ---- per-lane online softmax (16 scores, log2 domain) ----
        float mn = st[0];
        #pragma unroll
        for (int i = 1; i < 16; ++i) mn = fmaxf(mn, st[i]);
        mn = fmaxf(mn, __shfl_xor(mn, 32));
        float m2n = fmaxf(m2, mn);
        float alpha = exp2f(m2 - m2n);
        m2 = m2n;

        float pex[16], lsum = 0.f;
        #pragma unroll
        for (int i = 0; i < 16; ++i) {
            pex[i] = exp2f(st[i] - m2n);
            lsum += pex[i];
        }
        lsum += __shfl_xor(lsum, 32);
        l = l * alpha + lsum;

        if (__ballot(alpha != 1.0f)) {
            #pragma unroll
            for (int rg = 0; rg < 16; ++rg) {
                int rowv = (rg & 3) + 8 * (rg >> 2) + 4 * h;
                float av = __shfl(alpha, rowv);
                #pragma unroll
                for (int dt = 0; dt < 4; ++dt) acc[dt][rg] *= av;
            }
        }

        // ---- GEMM2: O += P.V, P reg half-exchange, V frags direct global ----
        #pragma unroll
        for (int s2 = 0; s2 < 2; ++s2) {
            unsigned int P0 = pkbf(pex[s2 * 8 + 0], pex[s2 * 8 + 1]);
            unsigned int P1 = pkbf(pex[s2 * 8 + 2], pex[s2 * 8 + 3]);
            unsigned int P2 = pkbf(pex[s2 * 8 + 4], pex[s2 * 8 + 5]);
            unsigned int P3 = pkbf(pex[s2 * 8 + 6], pex[s2 * 8 + 7]);
            unsigned int X0 = (unsigned int)__shfl_xor((int)P0, 32);
            unsigned int X1 = (unsigned int)__shfl_xor((int)P1, 32);
            unsigned int X2 = (unsigned int)__shfl_xor((int)P2, 32);
            unsigned int X3 = (unsigned int)__shfl_xor((int)P3, 32);
            union { unsigned int u[4]; s8v v; } pf;
            pf.u[0] = h ? X2 : P0;
            pf.u[1] = h ? X3 : P1;
            pf.u[2] = h ? P2 : X0;
            pf.u[3] = h ? P3 : X1;
            #pragma unroll
            for (int dt = 0; dt < 4; ++dt) {
                s8v vf = *(const s8v*)&Vb[((size_t)(lq + 32 * dt) << 13)
                                          + key0 + s2 * 16 + h * 8];
                acc[dt] = __builtin_amdgcn_mfma_f32_32x32x16_bf16(pf.v, vf, acc[dt], 0, 0, 0);
            }
        }
    }

    // ---- in-block 4-way merge: (0<-2), (1<-3), then (0<-1) ----
    if (w >= 2) {
        float* R = MB + (w - 2) * 4160;
        #pragma unroll
        for (int dt = 0; dt < 4; ++dt)
            #pragma unroll
            for (int rg = 0; rg < 16; ++rg) {
                int row = (rg & 3) + 8 * (rg >> 2) + 4 * h;
                R[row * 128 + lq + 32 * dt] = acc[dt][rg];
            }
        if (lane < 32) { R[4096 + lq] = m2; R[4128 + lq] = l; }
    }
    __syncthreads();
    if (w < 2) {
        float* R = MB + w * 4160;
        float mb = R[4096 + lq], lb = R[4128 + lq];
        float mF = fmaxf(m2, mb);
        float aA = exp2f(m2 - mF), aB = exp2f(mb - mF);
        l = l * aA + lb * aB; m2 = mF;
        #pragma unroll
        for (int rg = 0; rg < 16; ++rg) {
            int row = (rg & 3) + 8 * (rg >> 2) + 4 * h;
            float av = __shfl(aA, row), bv = __shfl(aB, row);
            #pragma unroll
            for (int dt = 0; dt < 4; ++dt)
                acc[dt][rg] = acc[dt][rg] * av + R[row * 128 + lq + 32 * dt] * bv;
        }
    }
    __syncthreads();
    if (w == 1) {
        float* R = MB;
        #pragma unroll
        for (int dt = 0; dt < 4; ++dt)
            #pragma unroll
            for (int rg = 0; rg < 16; ++rg) {
                int row = (rg & 3) + 8 * (rg >> 2) + 4 * h;
                R[row * 128 + lq + 32 * dt] = acc[dt][rg];
            }
        if (lane < 32) { R[4096 + lq] = m2; R[4128 + lq] = l; }
    }
    __syncthreads();
    if (w == 0) {
        float* R = MB;
        float mb = R[4096 + lq], lb = R[4128 + lq];
        float mF = fmaxf(m2, mb);
        float aA = exp2f(m2 - mF), aB = exp2f(mb - mF);
        l = l * aA + lb * aB; m2 = mF;
        _Float16* OP = (_Float16*)(pws + (size_t)id * PART_STRIDE);
        float* MLp = (float*)(pws + (size_t)id * PART_STRIDE + 8192);
        #pragma unroll
        for (int rg = 0; rg < 16; ++rg) {
            int row = (rg & 3) + 8 * (rg >> 2) + 4 * h;
            float av = __shfl(aA, row), bv = __shfl(aB, row);
            #pragma unroll
            for (int dt = 0; dt < 4; ++dt) {
                float o = acc[dt][rg] * av + R[row * 128 + lq + 32 * dt] * bv;
                OP[row * 128 + lq + 32 * dt] = (_Float16)o;
            }
        }
        if (lane < 32) { MLp[lq] = m2; MLp[32 + lq] = l; }
    }
}

// ---------------------------------------------------------------------------
// Final 2-way merge of block halves. grid 512 (b,qt), block 256.
// ---------------------------------------------------------------------------
__global__ __launch_bounds__(256, 2)
void merge_kernel(const unsigned char* __restrict__ pws, float* __restrict__ outp)
{
    const int bid = blockIdx.x;
    const int b = bid >> 8, qt = bid & 255;
    const int t = threadIdx.x;
    const int q = t >> 3, dc = t & 7;

    const int id0 = ((qt >> 1) << 3) | (b << 2) | (qt & 1);
    const int id1 = id0 | 2;

    const unsigned char* p0 = pws + (size_t)id0 * PART_STRIDE;
    const unsigned char* p1 = pws + (size_t)id1 * PART_STRIDE;
    const float* ml0 = (const float*)(p0 + 8192);
    const float* ml1 = (const float*)(p1 + 8192);
    float m0 = ml0[q], l0 = ml0[32 + q];
    float m1 = ml1[q], l1 = ml1[32 + q];
    float mF = fmaxf(m0, m1);
    float a0 = exp2f(m0 - mF), a1 = exp2f(m1 - mF);
    float inv = 1.f / (l0 * a0 + l1 * a1);
    a0 *= inv; a1 *= inv;

    const _Float16* O0 = (const _Float16*)p0;
    const _Float16* O1 = (const _Float16*)p1;
    const int base = q * 128 + dc * 16;
    float ov[16];
    #pragma unroll
    for (int c = 0; c < 16; ++c)
        ov[c] = (float)O0[base + c] * a0 + (float)O1[base + c] * a1;

    size_t ob = ((size_t)(b * NS + qt * 32 + q)) * NE + dc * 16;
    #pragma unroll
    for (int c = 0; c < 4; ++c)
        *(float4*)&outp[ob + c * 4] = *(float4*)&ov[c * 4];
}

// ---------------------------------------------------------------------------
extern "C" void kernel_launch(void* const* d_in, const int* in_sizes, int n_in,
                              void* d_out, int out_size, void* d_ws, size_t ws_size,
                              hipStream_t stream)
{
    const float* x  = (const float*)d_in[0];
    const float* Wq = (const float*)d_in[1];
    const float* bq = (const float*)d_in[2];
    const float* Wk = (const float*)d_in[3];
    const float* bk = (const float*)d_in[4];
    const float* Wv = (const float*)d_in[5];
    const float* bv = (const float*)d_in[6];
    float* out = (float*)d_out;

    unsigned char* ws = (unsigned char*)d_ws;
    unsigned short* qkv = (unsigned short*)ws;                 // 12.6 MB
    unsigned char* pws = ws + (size_t)3 * NROWS * NE * 2;      // 8.65 MB partials

    dim3 g1(NROWS / 32, 3, 2);
    qkv_kernel<<<g1, 256, 0, stream>>>(x, Wq, bq, Wk, bk, Wv, bv, qkv);

    attn_kernel<<<1024, 256, 0, stream>>>(qkv, pws);
    merge_kernel<<<512, 256, 0, stream>>>(pws, out);
}